// Round 3
// baseline (606.042 us; speedup 1.0000x reference)
//
#include <hip/hip_runtime.h>
#include <math.h>

#define NPIX 65536
#define NB   4
#define NK   6
#define TK   8
#define NBUK 48   // NK*TK
#define NCH  256
#define GSP  2    // plane split in k_accum
#define NSEL (NB*NK*TK)   // 192 selections
#define CCAP 65536        // per-(b,c) compacted list capacity (worst case all one class)

// ---------------- init: zero atomic targets + pass-0 histograms ----------------
__global__ __launch_bounds__(256) void k_init(unsigned* m_arr, unsigned* Mbits,
                                              unsigned* hist0) {
  int i = blockIdx.x * 256 + threadIdx.x;     // grid 8 -> 2048 threads
  if (i < NB * NK) { m_arr[i] = 0u; Mbits[i] = 0u; }
  for (int j = i; j < NB * NK * 256; j += 256 * 8) hist0[j] = 0u;   // 6144
}

// ---------------- A1: cert, argmax, per-class m/M, pass-0 hist, compaction ----------------
__global__ __launch_bounds__(256) void k_cert(const float* __restrict__ preds,
    float* __restrict__ cert, unsigned char* __restrict__ argm,
    unsigned* __restrict__ m_arr, unsigned* __restrict__ Mbits,
    unsigned* __restrict__ hist0, float* __restrict__ clist) {
  __shared__ unsigned s_cnt[NK], s_max[NK], s_base[NK];
  __shared__ unsigned s_hist[NK * 256];
  int tid = threadIdx.x;
  if (tid < NK) { s_cnt[tid] = 0u; s_max[tid] = 0u; }
  for (int j = tid; j < NK * 256; j += 256) s_hist[j] = 0u;
  __syncthreads();
  int i = blockIdx.x * 256 + tid;            // 4 pixels each; one batch per block
  int n4 = i << 2;
  int b = n4 >> 16;
  int n = n4 & (NPIX - 1);
  const float* pb = preds + (size_t)b * NK * NPIX + n;
  float4 pv[NK];
  #pragma unroll
  for (int k = 0; k < NK; ++k) pv[k] = *(const float4*)(pb + (size_t)k * NPIX);
  float cv[4]; unsigned av = 0; unsigned li[4]; int cls[4];
  #pragma unroll
  for (int j = 0; j < 4; ++j) {
    float m1 = -INFINITY, m2 = -INFINITY; int arg = 0;
    #pragma unroll
    for (int k = 0; k < NK; ++k) {
      float v = (j == 0) ? pv[k].x : (j == 1) ? pv[k].y : (j == 2) ? pv[k].z : pv[k].w;
      if (v > m1) { m2 = m1; m1 = v; arg = k; }
      else if (v > m2) m2 = v;
    }
    float c = m1 - m2;                        // >= 0
    cv[j] = c; cls[j] = arg;
    av |= ((unsigned)arg) << (8 * j);
    unsigned u = __float_as_uint(c);
    li[j] = atomicAdd(&s_cnt[arg], 1u);
    atomicMax(&s_max[arg], u);
    atomicAdd(&s_hist[arg * 256 + (u >> 24)], 1u);
  }
  *(float4*)(cert + (size_t)b * NPIX + n) = make_float4(cv[0], cv[1], cv[2], cv[3]);
  *(unsigned*)(argm + (size_t)b * NPIX + n) = av;
  __syncthreads();
  if (tid < NK) {
    s_base[tid] = atomicAdd(&m_arr[b * NK + tid], s_cnt[tid]);
    atomicMax(&Mbits[b * NK + tid], s_max[tid]);
  }
  for (int j = tid; j < NK * 256; j += 256)
    if (s_hist[j]) atomicAdd(&hist0[b * NK * 256 + j], s_hist[j]);
  __syncthreads();
  #pragma unroll
  for (int j = 0; j < 4; ++j)
    clist[((size_t)(b * NK + cls[j])) * CCAP + s_base[cls[j]] + li[j]] = cv[j];
}

// ---------------- A2: one block per (b,c); radix passes 1..3 over compacted list ----------
__global__ __launch_bounds__(256) void k_thresh24(const float* __restrict__ clist,
    const unsigned* __restrict__ hist0, const unsigned* __restrict__ m_arr,
    float* __restrict__ thr) {
  int bc = blockIdx.x;                       // 0..23
  int tid = threadIdx.x;
  __shared__ unsigned hist[TK * 256];        // 8 KB
  __shared__ unsigned s_pref[TK], s_rank[TK];
  __shared__ unsigned s_dp[TK];
  __shared__ int s_map[TK], s_ng;
  unsigned m = m_arr[bc];
  if (m == 0) { if (tid < TK) thr[bc * TK + tid] = 0.f; return; }
  if (tid < TK) {
    unsigned long long ks = ((unsigned long long)m * (unsigned)(tid + 1)) / TK;
    unsigned rk = ks ? (unsigned)ks : 1u;    // 1-based rank of threshold
    const unsigned* h = hist0 + bc * 256;    // pass-0 (top-8-bit) histogram
    unsigned cum = 0, pf = 0;
    for (int bin = 255; bin >= 0; --bin) {
      unsigned hh = h[bin]; cum += hh;
      if (cum >= rk) { pf = (unsigned)bin; rk = rk - (cum - hh); break; }
    }
    s_pref[tid] = pf; s_rank[tid] = rk;
  }
  __syncthreads();
  const float* lp = clist + (size_t)bc * CCAP;
  for (int pass = 1; pass < 4; ++pass) {
    int ps = 32 - 8 * pass, bs = 24 - 8 * pass;
    if (tid == 0) {                          // dedupe prefixes -> groups
      int ng = 0;
      for (int r = 0; r < TK; ++r) {
        int g = -1;
        for (int q = 0; q < ng; ++q) if (s_dp[q] == s_pref[r]) { g = q; break; }
        if (g < 0) { g = ng; s_dp[ng++] = s_pref[r]; }
        s_map[r] = g;
      }
      s_ng = ng;
    }
    for (int j = tid; j < TK * 256; j += 256) hist[j] = 0u;
    __syncthreads();
    int ng = s_ng;
    for (unsigned idx = tid; idx < m; idx += 256) {
      unsigned u = __float_as_uint(lp[idx]);
      unsigned top = u >> ps;
      for (int g = 0; g < ng; ++g)
        if (top == s_dp[g]) { atomicAdd(&hist[g * 256 + ((u >> bs) & 255u)], 1u); break; }
    }
    __syncthreads();
    if (tid < TK) {
      unsigned rk = s_rank[tid];
      const unsigned* h = &hist[s_map[tid] * 256];
      unsigned cum = 0;
      for (int bin = 255; bin >= 0; --bin) {
        unsigned hh = h[bin]; cum += hh;
        if (cum >= rk) { s_pref[tid] = (s_pref[tid] << 8) | (unsigned)bin; s_rank[tid] = rk - (cum - hh); break; }
      }
    }
    __syncthreads();
  }
  if (tid < TK) thr[bc * TK + tid] = __uint_as_float(s_pref[tid]);
}

// ---------------- A3: per-pixel packed (e | bucket) ----------------
__global__ __launch_bounds__(256) void k_bucket(const float* __restrict__ cert,
    const unsigned char* __restrict__ argm, const unsigned* __restrict__ Mbits,
    const float* __restrict__ thr, unsigned* __restrict__ eb_out) {
  __shared__ float s_thr[NSEL];
  __shared__ float s_M[NB * NK];
  int tid = threadIdx.x;
  if (tid < NSEL) s_thr[tid] = thr[tid];
  if (tid < NB * NK) s_M[tid] = __uint_as_float(Mbits[tid]);
  __syncthreads();
  int i = blockIdx.x * 256 + tid;
  int n4 = i << 2;
  int b = n4 >> 16;
  int n = n4 & (NPIX - 1);
  float4 cv = *(const float4*)(cert + (size_t)b * NPIX + n);
  unsigned av = *(const unsigned*)(argm + (size_t)b * NPIX + n);
  unsigned evv[4];
  #pragma unroll
  for (int j = 0; j < 4; ++j) {
    int c = (av >> (8 * j)) & 255;
    float ce = (j == 0) ? cv.x : (j == 1) ? cv.y : (j == 2) ? cv.z : cv.w;
    float e = expf(ce - s_M[b * NK + c]);
    const float* tc = &s_thr[(b * NK + c) * TK];
    int tmin = TK - 1;                        // every in-class pixel has ce >= thr[TK-1]
    #pragma unroll
    for (int tt = TK - 2; tt >= 0; --tt) if (ce >= tc[tt]) tmin = tt;
    evv[j] = (__float_as_uint(e) & 0xFFFFFFC0u) | (unsigned)(c * TK + tmin);
  }
  uint4 ev; ev.x = evv[0]; ev.y = evv[1]; ev.z = evv[2]; ev.w = evv[3];
  *(uint4*)(eb_out + (size_t)b * NPIX + n) = ev;
}

// ---------------- B: streaming pass over x; ds_add_f32 lane-owned buckets ----------------
// grid = NB*(NCH+1)*GSP; chz==NCH is the z-plane (x==1) for deterministic Z sums.
#define PROC(ev, xv) do { \
    unsigned u_; \
    u_ = ev.x; atomicAdd(&mycol[(u_ & 63u) * 64], xv.x * __uint_as_float(u_ & 0xFFFFFFC0u)); \
    u_ = ev.y; atomicAdd(&mycol[(u_ & 63u) * 64], xv.y * __uint_as_float(u_ & 0xFFFFFFC0u)); \
    u_ = ev.z; atomicAdd(&mycol[(u_ & 63u) * 64], xv.z * __uint_as_float(u_ & 0xFFFFFFC0u)); \
    u_ = ev.w; atomicAdd(&mycol[(u_ & 63u) * 64], xv.w * __uint_as_float(u_ & 0xFFFFFFC0u)); \
  } while (0)

__global__ __launch_bounds__(256) void k_accum(const float* __restrict__ x,
    const unsigned* __restrict__ eb, float* __restrict__ psum, float* __restrict__ zbuf) {
  __shared__ float acc[4 * NBUK * 64];        // [wave][bucket][lane]; lane-owned column
  __shared__ float wpart[4 * NBUK];
  int tid = threadIdx.x;
  int w = tid >> 6, lane = tid & 63;
  float* mycol = acc + (size_t)w * NBUK * 64 + lane;
  #pragma unroll
  for (int k = 0; k < NBUK; ++k) mycol[k * 64] = 0.f;
  __syncthreads();
  int blk = blockIdx.x;
  int g = blk & (GSP - 1);
  int pc = blk / GSP;
  int b = pc / (NCH + 1);
  int chz = pc % (NCH + 1);
  bool isz = (chz == NCH);
  const unsigned* ep = eb + (size_t)b * NPIX + g * (NPIX / GSP);
  const float* xp = x + ((size_t)b * NCH + chz) * NPIX + g * (NPIX / GSP);
  const int NIT = NPIX / GSP / 1024;          // 32
  int o = tid * 4;
  uint4 e0 = *(const uint4*)(ep + o);
  uint4 e1 = *(const uint4*)(ep + o + 1024);
  float4 x0 = make_float4(1.f, 1.f, 1.f, 1.f), x1 = x0;
  if (!isz) { x0 = *(const float4*)(xp + o); x1 = *(const float4*)(xp + o + 1024); }
  for (int it = 0; it < NIT; it += 2) {
    uint4 e2, e3; float4 x2, x3;
    bool more = (it + 2 < NIT);
    if (more) {
      e2 = *(const uint4*)(ep + o + (it + 2) * 1024);
      e3 = *(const uint4*)(ep + o + (it + 3) * 1024);
      if (!isz) {
        x2 = *(const float4*)(xp + o + (it + 2) * 1024);
        x3 = *(const float4*)(xp + o + (it + 3) * 1024);
      } else { x2 = make_float4(1.f, 1.f, 1.f, 1.f); x3 = x2; }
    }
    PROC(e0, x0);
    PROC(e1, x1);
    if (more) { e0 = e2; x0 = x2; e1 = e3; x1 = x3; }
  }
  __syncthreads();
  for (int k = 0; k < NBUK; ++k) {
    float v = mycol[k * 64];
    #pragma unroll
    for (int d = 1; d < 64; d <<= 1) v += __shfl_xor(v, d, 64);
    if (lane == 0) wpart[w * NBUK + k] = v;
  }
  __syncthreads();
  if (tid < NBUK) {
    float s = wpart[tid] + wpart[NBUK + tid] + wpart[2 * NBUK + tid] + wpart[3 * NBUK + tid];
    if (!isz) psum[((size_t)g * NB * NCH + (size_t)b * NCH + chz) * NBUK + tid] = s;
    else      zbuf[((size_t)g * NB + b) * NBUK + tid] = s;
  }
}

// ---------------- F: prefix over t, branch on m, write fs + fg ----------------
__global__ __launch_bounds__(256) void k_final(const float* __restrict__ psum,
    const float* __restrict__ zbuf, const unsigned* __restrict__ m_arr,
    float* __restrict__ out) {
  int i = blockIdx.x * 256 + threadIdx.x;     // (b, ch)
  if (i >= NB * NCH) return;
  int b = i >> 8;
  const float* ps0 = psum + (size_t)i * NBUK;
  const float* ps1 = psum + (size_t)NB * NCH * NBUK + (size_t)i * NBUK;
  const float* zb0 = zbuf + (size_t)b * NBUK;
  const float* zb1 = zbuf + (size_t)NB * NBUK + (size_t)b * NBUK;
  float* fs = out + (size_t)i * NBUK;
  float* fg = out + (size_t)NB * NCH * NBUK + (size_t)i * NK;
  float t5[TK];
  #pragma unroll
  for (int c = 0; c < NK; ++c) {
    unsigned m = m_arr[b * NK + c];
    float P = 0.f, Z = 0.f;
    float vals[TK];
    #pragma unroll
    for (int t = 0; t < TK; ++t) {
      P += ps0[c * TK + t] + ps1[c * TK + t];
      Z += zb0[c * TK + t] + zb1[c * TK + t];
      vals[t] = P / Z;
    }
    float tot = vals[TK - 1];
    #pragma unroll
    for (int t = 0; t < TK; ++t) {
      float v = (m == 0u) ? 0.f : ((m < (unsigned)TK) ? tot : vals[t]);
      fs[c * TK + t] = v;
      if (c == NK - 1) t5[t] = v;
    }
  }
  #pragma unroll
  for (int v = 0; v < NK; ++v) fg[v] = t5[2 + v];
}

extern "C" void kernel_launch(void* const* d_in, const int* in_sizes, int n_in,
                              void* d_out, int out_size, void* d_ws, size_t ws_size,
                              hipStream_t stream) {
  const float* x     = (const float*)d_in[0];   // [4,256,256,256]
  const float* preds = (const float*)d_in[1];   // [4,6,256,256]
  float* out = (float*)d_out;
  char* ws = (char*)d_ws;
  float*         cert  = (float*)(ws);                       // 1 MiB
  unsigned char* argm  = (unsigned char*)(ws + 0x100000);    // 256 KiB
  unsigned*      eb    = (unsigned*)(ws + 0x140000);         // 1 MiB
  float*         clist = (float*)(ws + 0x240000);            // 6 MiB (24 x 65536 f32)
  unsigned*      m_arr = (unsigned*)(ws + 0x840000);         // 24 u32
  unsigned*      Mbits = (unsigned*)(ws + 0x840100);         // 24 u32
  float*         thr   = (float*)(ws + 0x840200);            // 192 f32
  unsigned*      hist0 = (unsigned*)(ws + 0x841000);         // 24 KiB
  float*         psum  = (float*)(ws + 0x850000);            // 384 KiB
  float*         zbuf  = (float*)(ws + 0x8B0000);            // 1.5 KiB

  k_init    <<<8, 256, 0, stream>>>(m_arr, Mbits, hist0);
  k_cert    <<<256, 256, 0, stream>>>(preds, cert, argm, m_arr, Mbits, hist0, clist);
  k_thresh24<<<NB * NK, 256, 0, stream>>>(clist, hist0, m_arr, thr);
  k_bucket  <<<256, 256, 0, stream>>>(cert, argm, Mbits, thr, eb);
  k_accum   <<<NB * (NCH + 1) * GSP, 256, 0, stream>>>(x, eb, psum, zbuf);
  k_final   <<<4, 256, 0, stream>>>(psum, zbuf, m_arr, out);
}

// Round 4
// 463.179 us; speedup vs baseline: 1.3084x; 1.3084x over previous
//
#include <hip/hip_runtime.h>
#include <math.h>

#define NPIX 65536
#define NB   4
#define NK   6
#define TK   8
#define NBUK 48   // NK*TK
#define NCH  256
#define GSP  4    // plane split in k_accum
#define NSEL (NB*NK*TK)   // 192 selections

// ---------------- init: zero atomic targets + pass-0 histograms ----------------
__global__ __launch_bounds__(256) void k_init(unsigned* m_arr, unsigned* Mbits,
                                              unsigned* hist0) {
  int i = blockIdx.x * 256 + threadIdx.x;     // grid 8 -> 2048 threads
  if (i < NB * NK) { m_arr[i] = 0u; Mbits[i] = 0u; }
  for (int j = i; j < NB * NK * 256; j += 256 * 8) hist0[j] = 0u;   // 6144
}

// ---------------- A1: cert, argmax, per-class m/M, pass-0 radix histogram ----------------
__global__ __launch_bounds__(256) void k_cert(const float* __restrict__ preds,
    float* __restrict__ cert, unsigned char* __restrict__ argm,
    unsigned* __restrict__ m_arr, unsigned* __restrict__ Mbits,
    unsigned* __restrict__ hist0) {
  __shared__ unsigned s_cnt[NK], s_max[NK];
  __shared__ unsigned s_hist[NK * 256];
  int tid = threadIdx.x;
  if (tid < NK) { s_cnt[tid] = 0u; s_max[tid] = 0u; }
  for (int j = tid; j < NK * 256; j += 256) s_hist[j] = 0u;
  __syncthreads();
  int i = blockIdx.x * 256 + tid;            // 4 pixels each; one batch per block
  int n4 = i << 2;
  int b = n4 >> 16;
  int n = n4 & (NPIX - 1);
  const float* pb = preds + (size_t)b * NK * NPIX + n;
  float4 pv[NK];
  #pragma unroll
  for (int k = 0; k < NK; ++k) pv[k] = *(const float4*)(pb + (size_t)k * NPIX);
  float cv[4]; unsigned av = 0;
  #pragma unroll
  for (int j = 0; j < 4; ++j) {
    float m1 = -INFINITY, m2 = -INFINITY; int arg = 0;
    #pragma unroll
    for (int k = 0; k < NK; ++k) {
      float v = (j == 0) ? pv[k].x : (j == 1) ? pv[k].y : (j == 2) ? pv[k].z : pv[k].w;
      if (v > m1) { m2 = m1; m1 = v; arg = k; }
      else if (v > m2) m2 = v;
    }
    float c = m1 - m2;                        // >= 0
    cv[j] = c;
    av |= ((unsigned)arg) << (8 * j);
    unsigned u = __float_as_uint(c);
    atomicAdd(&s_cnt[arg], 1u);
    atomicMax(&s_max[arg], u);
    atomicAdd(&s_hist[arg * 256 + (u >> 24)], 1u);
  }
  *(float4*)(cert + (size_t)b * NPIX + n) = make_float4(cv[0], cv[1], cv[2], cv[3]);
  *(unsigned*)(argm + (size_t)b * NPIX + n) = av;
  __syncthreads();
  if (tid < NK) {
    if (s_cnt[tid]) atomicAdd(&m_arr[b * NK + tid], s_cnt[tid]);
    atomicMax(&Mbits[b * NK + tid], s_max[tid]);
  }
  for (int j = tid; j < NK * 256; j += 256)
    if (s_hist[j]) atomicAdd(&hist0[b * NK * 256 + j], s_hist[j]);
}

// ---------------- A2: one block per (b,c); radix passes 1..3 over cert/argm (L2-hot) ----
__global__ __launch_bounds__(1024) void k_thresh24(const float* __restrict__ cert,
    const unsigned char* __restrict__ argm, const unsigned* __restrict__ hist0,
    const unsigned* __restrict__ m_arr, float* __restrict__ thr) {
  int bc = blockIdx.x;                       // 0..23
  int b = bc / NK, c = bc % NK;
  int tid = threadIdx.x;
  __shared__ unsigned hist[TK * 256];        // 8 KB
  __shared__ unsigned s_pref[TK], s_rank[TK];
  __shared__ unsigned s_dp[TK];
  __shared__ int s_map[TK], s_ng;
  unsigned m = m_arr[bc];
  if (m == 0) { if (tid < TK) thr[bc * TK + tid] = 0.f; return; }
  if (tid < TK) {
    unsigned long long ks = ((unsigned long long)m * (unsigned)(tid + 1)) / TK;
    unsigned rk = ks ? (unsigned)ks : 1u;    // 1-based rank of threshold
    const unsigned* h = hist0 + bc * 256;    // pass-0 (top-8-bit) histogram
    unsigned cum = 0, pf = 0;
    for (int bin = 255; bin >= 0; --bin) {
      unsigned hh = h[bin]; cum += hh;
      if (cum >= rk) { pf = (unsigned)bin; rk = rk - (cum - hh); break; }
    }
    s_pref[tid] = pf; s_rank[tid] = rk;
  }
  __syncthreads();
  const float* cb = cert + (size_t)b * NPIX;
  const unsigned char* ab = argm + (size_t)b * NPIX;
  for (int pass = 1; pass < 4; ++pass) {
    int ps = 32 - 8 * pass, bs = 24 - 8 * pass;
    if (tid == 0) {                          // dedupe prefixes -> groups
      int ng = 0;
      for (int r = 0; r < TK; ++r) {
        int g = -1;
        for (int q = 0; q < ng; ++q) if (s_dp[q] == s_pref[r]) { g = q; break; }
        if (g < 0) { g = ng; s_dp[ng++] = s_pref[r]; }
        s_map[r] = g;
      }
      s_ng = ng;
    }
    for (int j = tid; j < TK * 256; j += 1024) hist[j] = 0u;
    __syncthreads();
    int ng = s_ng;
    for (int n0 = tid * 4; n0 < NPIX; n0 += 4096) {
      float4 cv = *(const float4*)(cb + n0);
      unsigned av = *(const unsigned*)(ab + n0);
      #pragma unroll
      for (int j = 0; j < 4; ++j) {
        if (((av >> (8 * j)) & 255u) == (unsigned)c) {
          unsigned u = __float_as_uint((j == 0) ? cv.x : (j == 1) ? cv.y : (j == 2) ? cv.z : cv.w);
          unsigned top = u >> ps;
          for (int g = 0; g < ng; ++g)
            if (top == s_dp[g]) { atomicAdd(&hist[g * 256 + ((u >> bs) & 255u)], 1u); break; }
        }
      }
    }
    __syncthreads();
    if (tid < TK) {
      unsigned rk = s_rank[tid];
      const unsigned* h = &hist[s_map[tid] * 256];
      unsigned cum = 0;
      for (int bin = 255; bin >= 0; --bin) {
        unsigned hh = h[bin]; cum += hh;
        if (cum >= rk) { s_pref[tid] = (s_pref[tid] << 8) | (unsigned)bin; s_rank[tid] = rk - (cum - hh); break; }
      }
    }
    __syncthreads();
  }
  if (tid < TK) thr[bc * TK + tid] = __uint_as_float(s_pref[tid]);
}

// ---------------- A3: per-pixel packed (e | bucket) ----------------
__global__ __launch_bounds__(256) void k_bucket(const float* __restrict__ cert,
    const unsigned char* __restrict__ argm, const unsigned* __restrict__ Mbits,
    const float* __restrict__ thr, unsigned* __restrict__ eb_out) {
  __shared__ float s_thr[NSEL];
  __shared__ float s_M[NB * NK];
  int tid = threadIdx.x;
  if (tid < NSEL) s_thr[tid] = thr[tid];
  if (tid < NB * NK) s_M[tid] = __uint_as_float(Mbits[tid]);
  __syncthreads();
  int i = blockIdx.x * 256 + tid;
  int n4 = i << 2;
  int b = n4 >> 16;
  int n = n4 & (NPIX - 1);
  float4 cv = *(const float4*)(cert + (size_t)b * NPIX + n);
  unsigned av = *(const unsigned*)(argm + (size_t)b * NPIX + n);
  unsigned evv[4];
  #pragma unroll
  for (int j = 0; j < 4; ++j) {
    int c = (av >> (8 * j)) & 255;
    float ce = (j == 0) ? cv.x : (j == 1) ? cv.y : (j == 2) ? cv.z : cv.w;
    float e = expf(ce - s_M[b * NK + c]);
    const float* tc = &s_thr[(b * NK + c) * TK];
    int tmin = TK - 1;                        // every in-class pixel has ce >= thr[TK-1]
    #pragma unroll
    for (int tt = TK - 2; tt >= 0; --tt) if (ce >= tc[tt]) tmin = tt;
    evv[j] = (__float_as_uint(e) & 0xFFFFFFC0u) | (unsigned)(c * TK + tmin);
  }
  uint4 ev; ev.x = evv[0]; ev.y = evv[1]; ev.z = evv[2]; ev.w = evv[3];
  *(uint4*)(eb_out + (size_t)b * NPIX + n) = ev;
}

// ---------------- B: pipelined pass over x; lane-owned LDS RMW buckets ----------------
// grid = NB*(NCH+1)*GSP; chz==NCH is the z-plane (x==1) for deterministic Z sums.
#define PROC(ev, xv) do { \
    unsigned u_; \
    u_ = ev.x; mycol[(u_ & 63u) * 64] += xv.x * __uint_as_float(u_ & 0xFFFFFFC0u); \
    u_ = ev.y; mycol[(u_ & 63u) * 64] += xv.y * __uint_as_float(u_ & 0xFFFFFFC0u); \
    u_ = ev.z; mycol[(u_ & 63u) * 64] += xv.z * __uint_as_float(u_ & 0xFFFFFFC0u); \
    u_ = ev.w; mycol[(u_ & 63u) * 64] += xv.w * __uint_as_float(u_ & 0xFFFFFFC0u); \
  } while (0)

__global__ __launch_bounds__(256) void k_accum(const float* __restrict__ x,
    const unsigned* __restrict__ eb, float* __restrict__ psum, float* __restrict__ zbuf) {
  __shared__ float acc[4 * NBUK * 64];        // [wave][bucket][lane]; lane-owned column
  __shared__ float wpart[4 * NBUK];
  int tid = threadIdx.x;
  int w = tid >> 6, lane = tid & 63;
  float* mycol = acc + (size_t)w * NBUK * 64 + lane;
  #pragma unroll
  for (int k = 0; k < NBUK; ++k) mycol[k * 64] = 0.f;
  __syncthreads();
  int blk = blockIdx.x;
  int g = blk & (GSP - 1);
  int pc = blk / GSP;
  int b = pc / (NCH + 1);
  int chz = pc % (NCH + 1);
  bool isz = (chz == NCH);
  const uint4*  ep4 = (const uint4*)(eb + (size_t)b * NPIX + g * (NPIX / GSP));
  const float4* xp4 = (const float4*)(x + ((size_t)b * NCH + chz) * NPIX + g * (NPIX / GSP));
  const int NIT = NPIX / GSP / 1024;          // 16 iterations of 1024 pixels
  const float4 ones = make_float4(1.f, 1.f, 1.f, 1.f);
  uint4 ebuf[4]; float4 xbuf[4];
  #pragma unroll
  for (int p = 0; p < 3; ++p) {               // prologue: prefetch 3 iterations
    ebuf[p] = ep4[tid + p * 256];
    xbuf[p] = isz ? ones : xp4[tid + p * 256];
  }
  #pragma unroll
  for (int it = 0; it < NIT; ++it) {          // fully unrolled -> static buffer indices
    if (it + 3 < NIT) {
      ebuf[(it + 3) & 3] = ep4[tid + (it + 3) * 256];
      xbuf[(it + 3) & 3] = isz ? ones : xp4[tid + (it + 3) * 256];
    }
    PROC(ebuf[it & 3], xbuf[it & 3]);
  }
  __syncthreads();
  for (int k = 0; k < NBUK; ++k) {
    float v = mycol[k * 64];
    #pragma unroll
    for (int d = 1; d < 64; d <<= 1) v += __shfl_xor(v, d, 64);
    if (lane == 0) wpart[w * NBUK + k] = v;
  }
  __syncthreads();
  if (tid < NBUK) {
    float s = wpart[tid] + wpart[NBUK + tid] + wpart[2 * NBUK + tid] + wpart[3 * NBUK + tid];
    if (!isz) psum[(((size_t)g * NB + b) * NCH + chz) * NBUK + tid] = s;
    else      zbuf[((size_t)g * NB + b) * NBUK + tid] = s;
  }
}

// ---------------- F: prefix over t, branch on m, write fs + fg ----------------
__global__ __launch_bounds__(256) void k_final(const float* __restrict__ psum,
    const float* __restrict__ zbuf, const unsigned* __restrict__ m_arr,
    float* __restrict__ out) {
  int i = blockIdx.x * 256 + threadIdx.x;     // (b, ch)
  if (i >= NB * NCH) return;
  int b = i >> 8;
  int ch = i & 255;
  float* fs = out + (size_t)i * NBUK;
  float* fg = out + (size_t)NB * NCH * NBUK + (size_t)i * NK;
  float t5[TK];
  #pragma unroll
  for (int c = 0; c < NK; ++c) {
    unsigned m = m_arr[b * NK + c];
    float P = 0.f, Z = 0.f;
    float vals[TK];
    #pragma unroll
    for (int t = 0; t < TK; ++t) {
      #pragma unroll
      for (int g = 0; g < GSP; ++g) {
        P += psum[(((size_t)g * NB + b) * NCH + ch) * NBUK + c * TK + t];
        Z += zbuf[((size_t)g * NB + b) * NBUK + c * TK + t];
      }
      vals[t] = P / Z;
    }
    float tot = vals[TK - 1];
    #pragma unroll
    for (int t = 0; t < TK; ++t) {
      float v = (m == 0u) ? 0.f : ((m < (unsigned)TK) ? tot : vals[t]);
      fs[c * TK + t] = v;
      if (c == NK - 1) t5[t] = v;
    }
  }
  #pragma unroll
  for (int v = 0; v < NK; ++v) fg[v] = t5[2 + v];
}

extern "C" void kernel_launch(void* const* d_in, const int* in_sizes, int n_in,
                              void* d_out, int out_size, void* d_ws, size_t ws_size,
                              hipStream_t stream) {
  const float* x     = (const float*)d_in[0];   // [4,256,256,256]
  const float* preds = (const float*)d_in[1];   // [4,6,256,256]
  float* out = (float*)d_out;
  char* ws = (char*)d_ws;
  float*         cert  = (float*)(ws);                       // 1 MiB
  unsigned char* argm  = (unsigned char*)(ws + 0x100000);    // 256 KiB
  unsigned*      eb    = (unsigned*)(ws + 0x140000);         // 1 MiB
  unsigned*      m_arr = (unsigned*)(ws + 0x240000);         // 24 u32
  unsigned*      Mbits = (unsigned*)(ws + 0x240100);         // 24 u32
  float*         thr   = (float*)(ws + 0x240200);            // 192 f32
  unsigned*      hist0 = (unsigned*)(ws + 0x241000);         // 24 KiB
  float*         psum  = (float*)(ws + 0x250000);            // 768 KiB (GSP=4)
  float*         zbuf  = (float*)(ws + 0x310000);            // 3 KiB

  k_init    <<<8, 256, 0, stream>>>(m_arr, Mbits, hist0);
  k_cert    <<<256, 256, 0, stream>>>(preds, cert, argm, m_arr, Mbits, hist0);
  k_thresh24<<<NB * NK, 1024, 0, stream>>>(cert, argm, hist0, m_arr, thr);
  k_bucket  <<<256, 256, 0, stream>>>(cert, argm, Mbits, thr, eb);
  k_accum   <<<NB * (NCH + 1) * GSP, 256, 0, stream>>>(x, eb, psum, zbuf);
  k_final   <<<4, 256, 0, stream>>>(psum, zbuf, m_arr, out);
}

// Round 5
// 202.169 us; speedup vs baseline: 2.9977x; 2.2910x over previous
//
#include <hip/hip_runtime.h>
#include <math.h>

#define NPIX 65536
#define NB   4
#define NK   6
#define TK   8
#define NBUK 48   // NK*TK
#define NCH  256
#define GSP  2    // plane split in k_accum
#define NSEL (NB*NK*TK)   // 192 selections
#define CCAP 65536        // per-(b,c) compacted list capacity

// ---------------- init: zero atomic targets ----------------
__global__ __launch_bounds__(64) void k_init(unsigned* m_arr, unsigned* Mbits) {
  int t = threadIdx.x;
  if (t < NB * NK) { m_arr[t] = 0u; Mbits[t] = 0u; }
}

// ---------------- A1: cert, argmax, per-class m/M, ballot-based compaction ----------------
__global__ __launch_bounds__(256) void k_cert(const float* __restrict__ preds,
    float* __restrict__ cert, unsigned char* __restrict__ argm,
    unsigned* __restrict__ m_arr, unsigned* __restrict__ Mbits,
    float* __restrict__ clist) {
  __shared__ unsigned s_max[NK];
  __shared__ unsigned s_seg[4][4][NK];      // [wave][j][class] counts
  __shared__ unsigned s_segbase[4][4][NK];  // exclusive offset within block
  __shared__ unsigned s_bbase[NK];          // global base for this block
  int tid = threadIdx.x;
  int w = tid >> 6, lane = tid & 63;
  if (tid < NK) s_max[tid] = 0u;
  __syncthreads();
  int i = blockIdx.x * 256 + tid;           // 4 pixels each; one batch per 64 blocks
  int n4 = i << 2;
  int b = n4 >> 16;
  int n = n4 & (NPIX - 1);
  const float* pb = preds + (size_t)b * NK * NPIX + n;
  float4 pv[NK];
  #pragma unroll
  for (int k = 0; k < NK; ++k) pv[k] = *(const float4*)(pb + (size_t)k * NPIX);
  float cv[4]; int cls[4]; unsigned av = 0;
  #pragma unroll
  for (int j = 0; j < 4; ++j) {
    float m1 = -INFINITY, m2 = -INFINITY; int arg = 0;
    #pragma unroll
    for (int k = 0; k < NK; ++k) {
      float v = (j == 0) ? pv[k].x : (j == 1) ? pv[k].y : (j == 2) ? pv[k].z : pv[k].w;
      if (v > m1) { m2 = m1; m1 = v; arg = k; }
      else if (v > m2) m2 = v;
    }
    cv[j] = m1 - m2;                        // >= 0
    cls[j] = arg;
    av |= ((unsigned)arg) << (8 * j);
    atomicMax(&s_max[arg], __float_as_uint(cv[j]));   // LDS u32, no-return
  }
  *(float4*)(cert + (size_t)b * NPIX + n) = make_float4(cv[0], cv[1], cv[2], cv[3]);
  *(unsigned*)(argm + (size_t)b * NPIX + n) = av;
  unsigned long long lmask = ((unsigned long long)1 << lane) - 1ull;
  unsigned myoff[4];
  #pragma unroll
  for (int j = 0; j < 4; ++j) {
    #pragma unroll
    for (int c = 0; c < NK; ++c) {
      unsigned long long mk = __ballot(cls[j] == c);
      if (cls[j] == c) myoff[j] = (unsigned)__popcll(mk & lmask);
      if (lane == 0) s_seg[w][j][c] = (unsigned)__popcll(mk);
    }
  }
  __syncthreads();
  if (tid < NK) {                           // one thread per class: scan 16 segments
    unsigned run = 0;
    #pragma unroll
    for (int s = 0; s < 16; ++s) {
      unsigned v = s_seg[s >> 2][s & 3][tid];
      s_segbase[s >> 2][s & 3][tid] = run;
      run += v;
    }
    s_bbase[tid] = atomicAdd(&m_arr[b * NK + tid], run);
    atomicMax(&Mbits[b * NK + tid], s_max[tid]);
  }
  __syncthreads();
  #pragma unroll
  for (int j = 0; j < 4; ++j) {
    int c = cls[j];
    clist[(size_t)(b * NK + c) * CCAP + s_bbase[c] + s_segbase[w][j][c] + myoff[j]] = cv[j];
  }
}

// ---------------- A2: one block per (b,c,t); 4 radix passes over compacted list ----------
__global__ __launch_bounds__(256) void k_thresh(const float* __restrict__ clist,
    const unsigned* __restrict__ m_arr, float* __restrict__ thr) {
  int g = blockIdx.x;                       // 0..191
  int bc = g >> 3;
  int t = g & 7;
  int tid = threadIdx.x;
  __shared__ unsigned hist[256];
  __shared__ unsigned s_sel, s_rank;
  unsigned m = m_arr[bc];
  if (m == 0) { if (tid == 0) thr[g] = 0.f; return; }
  unsigned long long ks = ((unsigned long long)m * (unsigned)(t + 1)) / TK;
  unsigned rank = ks ? (unsigned)ks : 1u;   // 1-based rank of threshold
  const unsigned* lp = (const unsigned*)clist + (size_t)bc * CCAP;
  unsigned prefix = 0;
  for (int pass = 0; pass < 4; ++pass) {
    int shift = 24 - 8 * pass;
    hist[tid] = 0u;
    __syncthreads();
    for (unsigned idx = tid; idx < m; idx += 256) {
      unsigned u = lp[idx];
      if (pass == 0 || (u >> (shift + 8)) == prefix)
        atomicAdd(&hist[(u >> shift) & 255u], 1u);
    }
    __syncthreads();
    if (tid == 0) {
      unsigned cum = 0, rn = rank, sel = 0;
      for (int bin = 255; bin >= 0; --bin) {
        unsigned hh = hist[bin]; cum += hh;
        if (cum >= rank) { sel = (unsigned)bin; rn = rank - (cum - hh); break; }
      }
      s_sel = sel; s_rank = rn;
    }
    __syncthreads();
    prefix = (prefix << 8) | s_sel;
    rank = s_rank;
    __syncthreads();
  }
  if (tid == 0) thr[g] = __uint_as_float(prefix);
}

// ---------------- A3: per-pixel packed (e | bucket) ----------------
__global__ __launch_bounds__(256) void k_bucket(const float* __restrict__ cert,
    const unsigned char* __restrict__ argm, const unsigned* __restrict__ Mbits,
    const float* __restrict__ thr, unsigned* __restrict__ eb_out) {
  __shared__ float s_thr[NSEL];
  __shared__ float s_M[NB * NK];
  int tid = threadIdx.x;
  if (tid < NSEL) s_thr[tid] = thr[tid];
  if (tid < NB * NK) s_M[tid] = __uint_as_float(Mbits[tid]);
  __syncthreads();
  int i = blockIdx.x * 256 + tid;
  int n4 = i << 2;
  int b = n4 >> 16;
  int n = n4 & (NPIX - 1);
  float4 cv = *(const float4*)(cert + (size_t)b * NPIX + n);
  unsigned av = *(const unsigned*)(argm + (size_t)b * NPIX + n);
  unsigned evv[4];
  #pragma unroll
  for (int j = 0; j < 4; ++j) {
    int c = (av >> (8 * j)) & 255;
    float ce = (j == 0) ? cv.x : (j == 1) ? cv.y : (j == 2) ? cv.z : cv.w;
    float e = expf(ce - s_M[b * NK + c]);
    const float* tc = &s_thr[(b * NK + c) * TK];
    int tmin = TK - 1;                      // in-class pixel always has ce >= thr[TK-1]
    #pragma unroll
    for (int tt = TK - 2; tt >= 0; --tt) if (ce >= tc[tt]) tmin = tt;
    evv[j] = (__float_as_uint(e) & 0xFFFFFFC0u) | (unsigned)(c * TK + tmin);
  }
  uint4 ev; ev.x = evv[0]; ev.y = evv[1]; ev.z = evv[2]; ev.w = evv[3];
  *(uint4*)(eb_out + (size_t)b * NPIX + n) = ev;
}

// ---------------- B: double-buffered pass over x; lane-owned LDS RMW buckets ----------------
// grid = NB*(NCH+1)*GSP; chz==NCH is the z-plane (x==1) for deterministic Z sums.
#define PROC(ev, xv) do { \
    unsigned u_; \
    u_ = ev.x; mycol[(u_ & 63u) * 64] += xv.x * __uint_as_float(u_ & 0xFFFFFFC0u); \
    u_ = ev.y; mycol[(u_ & 63u) * 64] += xv.y * __uint_as_float(u_ & 0xFFFFFFC0u); \
    u_ = ev.z; mycol[(u_ & 63u) * 64] += xv.z * __uint_as_float(u_ & 0xFFFFFFC0u); \
    u_ = ev.w; mycol[(u_ & 63u) * 64] += xv.w * __uint_as_float(u_ & 0xFFFFFFC0u); \
  } while (0)

__global__ __launch_bounds__(256) void k_accum(const float* __restrict__ x,
    const unsigned* __restrict__ eb, float* __restrict__ psum, float* __restrict__ zbuf) {
  __shared__ float acc[4 * NBUK * 64];      // [wave][bucket][lane]; lane-owned column
  __shared__ float wpart[4 * NBUK];
  int tid = threadIdx.x;
  int w = tid >> 6, lane = tid & 63;
  float* mycol = acc + (size_t)w * NBUK * 64 + lane;
  #pragma unroll
  for (int k = 0; k < NBUK; ++k) mycol[k * 64] = 0.f;
  __syncthreads();
  int blk = blockIdx.x;
  int g = blk & (GSP - 1);
  int pc = blk / GSP;
  int b = pc / (NCH + 1);
  int chz = pc % (NCH + 1);
  bool isz = (chz == NCH);
  const uint4*  ep4 = (const uint4*)(eb + (size_t)b * NPIX + g * (NPIX / GSP));
  const float4* xp4 = (const float4*)(x + ((size_t)b * NCH + chz) * NPIX + g * (NPIX / GSP));
  const int NIT = NPIX / GSP / 2048;        // 16 iterations of 2048 pixels
  const float4 ones = make_float4(1.f, 1.f, 1.f, 1.f);
  // double-buffered sets, fully static
  uint4 ea0, eb0, ea1, eb1; float4 xa0, xb0, xa1, xb1;
  ea0 = ep4[tid];       eb0 = ep4[tid + 256];
  xa0 = isz ? ones : xp4[tid];
  xb0 = isz ? ones : xp4[tid + 256];
  #pragma unroll
  for (int it = 0; it < NIT; it += 2) {
    int base1 = (it + 1) * 512;
    ea1 = ep4[base1 + tid]; eb1 = ep4[base1 + tid + 256];
    xa1 = isz ? ones : xp4[base1 + tid];
    xb1 = isz ? ones : xp4[base1 + tid + 256];
    PROC(ea0, xa0); PROC(eb0, xb0);
    if (it + 2 < NIT) {
      int base2 = (it + 2) * 512;
      ea0 = ep4[base2 + tid]; eb0 = ep4[base2 + tid + 256];
      xa0 = isz ? ones : xp4[base2 + tid];
      xb0 = isz ? ones : xp4[base2 + tid + 256];
    }
    PROC(ea1, xa1); PROC(eb1, xb1);
  }
  __syncthreads();
  for (int k = 0; k < NBUK; ++k) {
    float v = mycol[k * 64];
    #pragma unroll
    for (int d = 1; d < 64; d <<= 1) v += __shfl_xor(v, d, 64);
    if (lane == 0) wpart[w * NBUK + k] = v;
  }
  __syncthreads();
  if (tid < NBUK) {
    float s = wpart[tid] + wpart[NBUK + tid] + wpart[2 * NBUK + tid] + wpart[3 * NBUK + tid];
    if (!isz) psum[(((size_t)g * NB + b) * NCH + chz) * NBUK + tid] = s;
    else      zbuf[((size_t)g * NB + b) * NBUK + tid] = s;
  }
}

// ---------------- F: prefix over t, branch on m, write fs + fg ----------------
__global__ __launch_bounds__(256) void k_final(const float* __restrict__ psum,
    const float* __restrict__ zbuf, const unsigned* __restrict__ m_arr,
    float* __restrict__ out) {
  int i = blockIdx.x * 256 + threadIdx.x;   // (b, ch)
  if (i >= NB * NCH) return;
  int b = i >> 8;
  int ch = i & 255;
  float* fs = out + (size_t)i * NBUK;
  float* fg = out + (size_t)NB * NCH * NBUK + (size_t)i * NK;
  float t5[TK];
  #pragma unroll
  for (int c = 0; c < NK; ++c) {
    unsigned m = m_arr[b * NK + c];
    float P = 0.f, Z = 0.f;
    float vals[TK];
    #pragma unroll
    for (int t = 0; t < TK; ++t) {
      #pragma unroll
      for (int g = 0; g < GSP; ++g) {
        P += psum[(((size_t)g * NB + b) * NCH + ch) * NBUK + c * TK + t];
        Z += zbuf[((size_t)g * NB + b) * NBUK + c * TK + t];
      }
      vals[t] = P / Z;
    }
    float tot = vals[TK - 1];
    #pragma unroll
    for (int t = 0; t < TK; ++t) {
      float v = (m == 0u) ? 0.f : ((m < (unsigned)TK) ? tot : vals[t]);
      fs[c * TK + t] = v;
      if (c == NK - 1) t5[t] = v;
    }
  }
  #pragma unroll
  for (int v = 0; v < NK; ++v) fg[v] = t5[2 + v];
}

extern "C" void kernel_launch(void* const* d_in, const int* in_sizes, int n_in,
                              void* d_out, int out_size, void* d_ws, size_t ws_size,
                              hipStream_t stream) {
  const float* x     = (const float*)d_in[0];   // [4,256,256,256]
  const float* preds = (const float*)d_in[1];   // [4,6,256,256]
  float* out = (float*)d_out;
  char* ws = (char*)d_ws;
  float*         cert  = (float*)(ws);                       // 1 MiB
  unsigned char* argm  = (unsigned char*)(ws + 0x100000);    // 256 KiB
  unsigned*      eb    = (unsigned*)(ws + 0x140000);         // 1 MiB
  float*         clist = (float*)(ws + 0x240000);            // 6 MiB (24 x 65536 f32)
  unsigned*      m_arr = (unsigned*)(ws + 0x840000);         // 24 u32
  unsigned*      Mbits = (unsigned*)(ws + 0x840100);         // 24 u32
  float*         thr   = (float*)(ws + 0x840200);            // 192 f32
  float*         psum  = (float*)(ws + 0x850000);            // 384 KiB (GSP=2)
  float*         zbuf  = (float*)(ws + 0x8D0000);            // 1.5 KiB

  k_init  <<<1, 64, 0, stream>>>(m_arr, Mbits);
  k_cert  <<<256, 256, 0, stream>>>(preds, cert, argm, m_arr, Mbits, clist);
  k_thresh<<<NSEL, 256, 0, stream>>>(clist, m_arr, thr);
  k_bucket<<<256, 256, 0, stream>>>(cert, argm, Mbits, thr, eb);
  k_accum <<<NB * (NCH + 1) * GSP, 256, 0, stream>>>(x, eb, psum, zbuf);
  k_final <<<4, 256, 0, stream>>>(psum, zbuf, m_arr, out);
}